// Round 1
// baseline (396.337 us; speedup 1.0000x reference)
//
#include <hip/hip_runtime.h>
#include <hip/hip_cooperative_groups.h>
#include <math.h>

namespace cg = cooperative_groups;

#define L_ 200

// ============================================================================
// Fused single-launch pipeline: pool -> gemm+stats -> bn -> head -> loss
// 256 blocks x 256 threads (1 block/CU, trivially co-resident for grid.sync)
// ============================================================================
__global__ __launch_bounds__(256) void fused_kernel(
    const int* __restrict__ tokens, const int* __restrict__ lengths,
    const float* __restrict__ t, const float* __restrict__ emb,
    const float* __restrict__ W1, const float* __restrict__ b1,
    const float* __restrict__ gamma, const float* __restrict__ beta,
    const float* __restrict__ w2, const float* __restrict__ b2,
    float* __restrict__ pooled, float* __restrict__ z, float* __restrict__ W1p,
    float* __restrict__ psum, float* __restrict__ psq,
    float* __restrict__ A, float* __restrict__ C,
    float* __restrict__ bpart, float* __restrict__ out) {
  cg::grid_group grid = cg::this_grid();
  __shared__ float4 SH[1024];   // 16 KB, reused across phases
  float* SHf = (float*)SH;
  const int tid = threadIdx.x;
  const int wv = tid >> 6, lane = tid & 63;

  // ---------------- phase 1: pooling (persistent over 2048 virtual blocks)
  // + W1 transpose-pack piggybacked on vb<64 ----------------
  const float4* embv = (const float4*)emb;
  for (int vb = blockIdx.x; vb < 2048; vb += 256) {
    if (vb < 64) {
      float4 v = ((const float4*)W1)[tid * 64 + vb];
      ((float4*)W1p)[vb * 256 + tid] = v;
    }
    const int row = vb * 2 + (wv >> 1);
    const int half = wv & 1;
    const int len = lengths[row];
    const int* trow = tokens + row * L_;
    float4 a0 = make_float4(0.f, 0.f, 0.f, 0.f);
    float4 a1 = a0, a2 = a0, a3 = a0, a4 = a0, a5 = a0, a6 = a0, a7 = a0;
    for (int l0 = half * 64; l0 < len; l0 += 128) {
      int nt = len - l0; nt = nt > 64 ? 64 : nt;
      int tk = (lane < nt) ? trow[l0 + lane] : 0;   // coalesced token load
      int j = 0;
      for (; j + 8 <= nt; j += 8) {                 // 8 gathers in flight
        int t0 = __shfl(tk, j);
        int t1 = __shfl(tk, j + 1);
        int t2 = __shfl(tk, j + 2);
        int t3 = __shfl(tk, j + 3);
        int t4 = __shfl(tk, j + 4);
        int t5 = __shfl(tk, j + 5);
        int t6 = __shfl(tk, j + 6);
        int t7 = __shfl(tk, j + 7);
        float4 v0 = embv[(size_t)t0 * 64 + lane];
        float4 v1 = embv[(size_t)t1 * 64 + lane];
        float4 v2 = embv[(size_t)t2 * 64 + lane];
        float4 v3 = embv[(size_t)t3 * 64 + lane];
        float4 v4 = embv[(size_t)t4 * 64 + lane];
        float4 v5 = embv[(size_t)t5 * 64 + lane];
        float4 v6 = embv[(size_t)t6 * 64 + lane];
        float4 v7 = embv[(size_t)t7 * 64 + lane];
        a0.x += v0.x; a0.y += v0.y; a0.z += v0.z; a0.w += v0.w;
        a1.x += v1.x; a1.y += v1.y; a1.z += v1.z; a1.w += v1.w;
        a2.x += v2.x; a2.y += v2.y; a2.z += v2.z; a2.w += v2.w;
        a3.x += v3.x; a3.y += v3.y; a3.z += v3.z; a3.w += v3.w;
        a4.x += v4.x; a4.y += v4.y; a4.z += v4.z; a4.w += v4.w;
        a5.x += v5.x; a5.y += v5.y; a5.z += v5.z; a5.w += v5.w;
        a6.x += v6.x; a6.y += v6.y; a6.z += v6.z; a6.w += v6.w;
        a7.x += v7.x; a7.y += v7.y; a7.z += v7.z; a7.w += v7.w;
      }
      for (; j + 4 <= nt; j += 4) {
        int t0 = __shfl(tk, j);
        int t1 = __shfl(tk, j + 1);
        int t2 = __shfl(tk, j + 2);
        int t3 = __shfl(tk, j + 3);
        float4 v0 = embv[(size_t)t0 * 64 + lane];
        float4 v1 = embv[(size_t)t1 * 64 + lane];
        float4 v2 = embv[(size_t)t2 * 64 + lane];
        float4 v3 = embv[(size_t)t3 * 64 + lane];
        a0.x += v0.x; a0.y += v0.y; a0.z += v0.z; a0.w += v0.w;
        a1.x += v1.x; a1.y += v1.y; a1.z += v1.z; a1.w += v1.w;
        a2.x += v2.x; a2.y += v2.y; a2.z += v2.z; a2.w += v2.w;
        a3.x += v3.x; a3.y += v3.y; a3.z += v3.z; a3.w += v3.w;
      }
      for (; j < nt; j++) {
        int t0 = __shfl(tk, j);
        float4 v0 = embv[(size_t)t0 * 64 + lane];
        a0.x += v0.x; a0.y += v0.y; a0.z += v0.z; a0.w += v0.w;
      }
    }
    float4 r;
    r.x = ((a0.x + a1.x) + (a2.x + a3.x)) + ((a4.x + a5.x) + (a6.x + a7.x));
    r.y = ((a0.y + a1.y) + (a2.y + a3.y)) + ((a4.y + a5.y) + (a6.y + a7.y));
    r.z = ((a0.z + a1.z) + (a2.z + a3.z)) + ((a4.z + a5.z) + (a6.z + a7.z));
    r.w = ((a0.w + a1.w) + (a2.w + a3.w)) + ((a4.w + a5.w) + (a6.w + a7.w));
    __syncthreads();   // previous iteration's SH readers done
    if (half) SH[(wv >> 1) * 64 + lane] = r;
    __syncthreads();
    if (!half) {
      float4 o = SH[(wv >> 1) * 64 + lane];
      const float inv = 1.0f / (float)len;
      r.x = (r.x + o.x) * inv;
      r.y = (r.y + o.y) * inv;
      r.z = (r.z + o.z) * inv;
      r.w = (r.w + o.w) * inv;
      ((float4*)pooled)[(size_t)row * 64 + lane] = r;
    }
  }
  grid.sync();

  // ---------------- phase 2: z = pooled @ W1^T + b1, per-block BN partials
  // (identical structure to verified gemm_stats_kernel; 256 blocks x 16 rows)
  {
    const int b0 = blockIdx.x * 16;
    const float4* pooled4 = (const float4*)pooled;
#pragma unroll
    for (int i = 0; i < 4; i++)
      SH[tid + i * 256] = pooled4[(size_t)b0 * 64 + tid + i * 256];
    __syncthreads();
    const int r0 = wv * 4;
    float4 bb = ((const float4*)b1)[lane];
    float acc[4][4];
#pragma unroll
    for (int r = 0; r < 4; r++) {
      acc[r][0] = bb.x; acc[r][1] = bb.y; acc[r][2] = bb.z; acc[r][3] = bb.w;
    }
    const float4* w4 = (const float4*)W1p;
    for (int kb = 0; kb < 64; kb++) {
      float4 wk0 = w4[kb * 256 + lane * 4 + 0];
      float4 wk1 = w4[kb * 256 + lane * 4 + 1];
      float4 wk2 = w4[kb * 256 + lane * 4 + 2];
      float4 wk3 = w4[kb * 256 + lane * 4 + 3];
#pragma unroll
      for (int r = 0; r < 4; r++) {
        float4 p = SH[(r0 + r) * 64 + kb];   // wave-uniform -> LDS broadcast
        acc[r][0] += p.x * wk0.x + p.y * wk0.y + p.z * wk0.z + p.w * wk0.w;
        acc[r][1] += p.x * wk1.x + p.y * wk1.y + p.z * wk1.z + p.w * wk1.w;
        acc[r][2] += p.x * wk2.x + p.y * wk2.y + p.z * wk2.z + p.w * wk2.w;
        acc[r][3] += p.x * wk3.x + p.y * wk3.y + p.z * wk3.z + p.w * wk3.w;
      }
    }
    float4* z4 = (float4*)z;
    float4 s = make_float4(0.f, 0.f, 0.f, 0.f), q = s;
#pragma unroll
    for (int r = 0; r < 4; r++) {
      float4 o = make_float4(acc[r][0], acc[r][1], acc[r][2], acc[r][3]);
      z4[(size_t)(b0 + r0 + r) * 64 + lane] = o;
      s.x += o.x; s.y += o.y; s.z += o.z; s.w += o.w;
      q.x += o.x * o.x; q.y += o.y * o.y; q.z += o.z * o.z; q.w += o.w * o.w;
    }
    __syncthreads();   // done reading pooled tile; reuse SH for stats
    SH[wv * 64 + lane] = s;
    SH[256 + wv * 64 + lane] = q;
    __syncthreads();
    if (tid < 64) {
      float4 S = make_float4(0.f, 0.f, 0.f, 0.f), Q = S;
#pragma unroll
      for (int w = 0; w < 4; w++) {
        float4 a = SH[w * 64 + tid];
        float4 b = SH[256 + w * 64 + tid];
        S.x += a.x; S.y += a.y; S.z += a.z; S.w += a.w;
        Q.x += b.x; Q.y += b.y; Q.z += b.z; Q.w += b.w;
      }
      ((float4*)psum)[blockIdx.x * 64 + tid] = S;
      ((float4*)psq)[blockIdx.x * 64 + tid] = Q;
    }
  }
  grid.sync();

  // ---------------- phase 3: BN finalize, one block per dim ----------------
  {
    const int d = blockIdx.x;
    float s = psum[tid * 256 + d];
    float q = psq[tid * 256 + d];
#pragma unroll
    for (int off = 32; off > 0; off >>= 1) {
      s += __shfl_down(s, off);
      q += __shfl_down(q, off);
    }
    if (lane == 0) { SHf[wv] = s; SHf[8 + wv] = q; }
    __syncthreads();
    if (tid == 0) {
      float S = (SHf[0] + SHf[1]) + (SHf[2] + SHf[3]);
      float Q = (SHf[8] + SHf[9]) + (SHf[10] + SHf[11]);
      float m = S * (1.0f / 4096.0f);
      float v = Q * (1.0f / 4096.0f) - m * m;
      float a = gamma[d] * rsqrtf(v + 1e-5f);
      A[d] = a;
      C[d] = beta[d] - m * a;
    }
  }
  grid.sync();

  // ---------------- phase 4: BN-apply + ReLU + dot head + per-row BCE
  // persistent over 1024 virtual blocks; per-block BCE partial ----------------
  {
    float4 A4 = ((const float4*)A)[lane];
    float4 C4 = ((const float4*)C)[lane];
    float4 w24 = ((const float4*)w2)[lane];
    float b2v = b2[0];
    float bsum = 0.f;
    for (int hb = blockIdx.x; hb < 1024; hb += 256) {
      const int b = hb * 4 + wv;
      float4 zv = ((const float4*)z)[(size_t)b * 64 + lane];
      float h0 = fmaxf(A4.x * zv.x + C4.x, 0.f);
      float h1 = fmaxf(A4.y * zv.y + C4.y, 0.f);
      float h2 = fmaxf(A4.z * zv.z + C4.z, 0.f);
      float h3 = fmaxf(A4.w * zv.w + C4.w, 0.f);
      float part = h0 * w24.x + h1 * w24.y + h2 * w24.z + h3 * w24.w;
#pragma unroll
      for (int off = 32; off > 0; off >>= 1) part += __shfl_down(part, off);
      if (lane == 0) {
        float logit = part + b2v;
        out[1 + b] = logit;
        float tb = t[b];
        bsum += fmaxf(logit, 0.f) - logit * tb + log1pf(expf(-fabsf(logit)));
      }
    }
    __syncthreads();   // SHf free (phase 3 consumers done grid-wide)
    if (lane == 0) SHf[wv] = bsum;
    __syncthreads();
    if (tid == 0) bpart[blockIdx.x] = (SHf[0] + SHf[1]) + (SHf[2] + SHf[3]);
  }
  grid.sync();

  // ---------------- phase 5: deterministic loss reduction (block 0) --------
  if (blockIdx.x == 0) {
    float s = bpart[tid];
#pragma unroll
    for (int off = 32; off > 0; off >>= 1) s += __shfl_down(s, off);
    __syncthreads();
    if (lane == 0) SHf[wv] = s;
    __syncthreads();
    if (tid == 0) out[0] = ((SHf[0] + SHf[1]) + (SHf[2] + SHf[3])) * (1.0f / 4096.0f);
  }
}

// ============================================================================
// Fallback path: verified 5-kernel pipeline (launched only if cooperative
// launch fails)
// ============================================================================
__global__ __launch_bounds__(256) void pool_pack_kernel(
    const int* __restrict__ tokens, const int* __restrict__ lengths,
    const float* __restrict__ emb, float* __restrict__ pooled,
    const float* __restrict__ W1, float* __restrict__ W1p) {
  const int tid = threadIdx.x;
  if (blockIdx.x < 64) {
    float4 v = ((const float4*)W1)[tid * 64 + blockIdx.x];
    ((float4*)W1p)[blockIdx.x * 256 + tid] = v;
  }
  const int wv = tid >> 6, lane = tid & 63;
  const int row = blockIdx.x * 2 + (wv >> 1);
  const int half = wv & 1;
  const int len = lengths[row];
  const int* trow = tokens + row * L_;
  const float4* embv = (const float4*)emb;
  float4 a0 = make_float4(0.f, 0.f, 0.f, 0.f);
  float4 a1 = a0, a2 = a0, a3 = a0;
  for (int l0 = half * 64; l0 < len; l0 += 128) {
    int nt = len - l0; nt = nt > 64 ? 64 : nt;
    int tk = (lane < nt) ? trow[l0 + lane] : 0;
    int j = 0;
    for (; j + 4 <= nt; j += 4) {
      int t0 = __shfl(tk, j);
      int t1 = __shfl(tk, j + 1);
      int t2 = __shfl(tk, j + 2);
      int t3 = __shfl(tk, j + 3);
      float4 v0 = embv[(size_t)t0 * 64 + lane];
      float4 v1 = embv[(size_t)t1 * 64 + lane];
      float4 v2 = embv[(size_t)t2 * 64 + lane];
      float4 v3 = embv[(size_t)t3 * 64 + lane];
      a0.x += v0.x; a0.y += v0.y; a0.z += v0.z; a0.w += v0.w;
      a1.x += v1.x; a1.y += v1.y; a1.z += v1.z; a1.w += v1.w;
      a2.x += v2.x; a2.y += v2.y; a2.z += v2.z; a2.w += v2.w;
      a3.x += v3.x; a3.y += v3.y; a3.z += v3.z; a3.w += v3.w;
    }
    for (; j < nt; j++) {
      int t0 = __shfl(tk, j);
      float4 v0 = embv[(size_t)t0 * 64 + lane];
      a0.x += v0.x; a0.y += v0.y; a0.z += v0.z; a0.w += v0.w;
    }
  }
  float4 r;
  r.x = a0.x + a1.x + a2.x + a3.x;
  r.y = a0.y + a1.y + a2.y + a3.y;
  r.z = a0.z + a1.z + a2.z + a3.z;
  r.w = a0.w + a1.w + a2.w + a3.w;
  __shared__ float4 part[2][64];
  if (half) part[wv >> 1][lane] = r;
  __syncthreads();
  if (!half) {
    float4 o = part[wv >> 1][lane];
    const float inv = 1.0f / (float)len;
    r.x = (r.x + o.x) * inv;
    r.y = (r.y + o.y) * inv;
    r.z = (r.z + o.z) * inv;
    r.w = (r.w + o.w) * inv;
    ((float4*)pooled)[(size_t)row * 64 + lane] = r;
  }
}

__global__ __launch_bounds__(256) void gemm_stats_kernel(
    const float* __restrict__ pooled, const float* __restrict__ W1p,
    const float* __restrict__ b1, float* __restrict__ z,
    float* __restrict__ psum, float* __restrict__ psq) {
  __shared__ float4 SH[1024];
  const int tid = threadIdx.x;
  const int b0 = blockIdx.x * 16;
  const float4* pooled4 = (const float4*)pooled;
#pragma unroll
  for (int i = 0; i < 4; i++)
    SH[tid + i * 256] = pooled4[(size_t)b0 * 64 + tid + i * 256];
  __syncthreads();
  const int wv = tid >> 6, lane = tid & 63;
  const int r0 = wv * 4;
  float4 bb = ((const float4*)b1)[lane];
  float acc[4][4];
#pragma unroll
  for (int r = 0; r < 4; r++) {
    acc[r][0] = bb.x; acc[r][1] = bb.y; acc[r][2] = bb.z; acc[r][3] = bb.w;
  }
  const float4* w4 = (const float4*)W1p;
  for (int kb = 0; kb < 64; kb++) {
    float4 wk0 = w4[kb * 256 + lane * 4 + 0];
    float4 wk1 = w4[kb * 256 + lane * 4 + 1];
    float4 wk2 = w4[kb * 256 + lane * 4 + 2];
    float4 wk3 = w4[kb * 256 + lane * 4 + 3];
#pragma unroll
    for (int r = 0; r < 4; r++) {
      float4 p = SH[(r0 + r) * 64 + kb];
      acc[r][0] += p.x * wk0.x + p.y * wk0.y + p.z * wk0.z + p.w * wk0.w;
      acc[r][1] += p.x * wk1.x + p.y * wk1.y + p.z * wk1.z + p.w * wk1.w;
      acc[r][2] += p.x * wk2.x + p.y * wk2.y + p.z * wk2.z + p.w * wk2.w;
      acc[r][3] += p.x * wk3.x + p.y * wk3.y + p.z * wk3.z + p.w * wk3.w;
    }
  }
  float4* z4 = (float4*)z;
  float4 s = make_float4(0.f, 0.f, 0.f, 0.f), q = s;
#pragma unroll
  for (int r = 0; r < 4; r++) {
    float4 o = make_float4(acc[r][0], acc[r][1], acc[r][2], acc[r][3]);
    z4[(size_t)(b0 + r0 + r) * 64 + lane] = o;
    s.x += o.x; s.y += o.y; s.z += o.z; s.w += o.w;
    q.x += o.x * o.x; q.y += o.y * o.y; q.z += o.z * o.z; q.w += o.w * o.w;
  }
  __syncthreads();
  SH[wv * 64 + lane] = s;
  SH[256 + wv * 64 + lane] = q;
  __syncthreads();
  if (tid < 64) {
    float4 S = make_float4(0.f, 0.f, 0.f, 0.f), Q = S;
#pragma unroll
    for (int w = 0; w < 4; w++) {
      float4 a = SH[w * 64 + tid];
      float4 b = SH[256 + w * 64 + tid];
      S.x += a.x; S.y += a.y; S.z += a.z; S.w += a.w;
      Q.x += b.x; Q.y += b.y; Q.z += b.z; Q.w += b.w;
    }
    ((float4*)psum)[blockIdx.x * 64 + tid] = S;
    ((float4*)psq)[blockIdx.x * 64 + tid] = Q;
  }
}

__global__ __launch_bounds__(256) void bn_reduce_kernel(
    const float* __restrict__ psum, const float* __restrict__ psq,
    const float* __restrict__ gamma, const float* __restrict__ beta,
    float* __restrict__ A, float* __restrict__ C) {
  const int t = threadIdx.x;
  const int dd = t & 15, c = t >> 4;
  const int d = blockIdx.x * 16 + dd;
  float s = 0.f, q = 0.f;
#pragma unroll
  for (int i = 0; i < 16; i++) {
    int p = c * 16 + i;
    s += psum[p * 256 + d];
    q += psq[p * 256 + d];
  }
  __shared__ float sl[16][17], ql[16][17];
  sl[c][dd] = s; ql[c][dd] = q;
  __syncthreads();
  if (t < 16) {
    float S = 0.f, Q = 0.f;
#pragma unroll
    for (int c2 = 0; c2 < 16; c2++) { S += sl[c2][t]; Q += ql[c2][t]; }
    int dg = blockIdx.x * 16 + t;
    float m = S * (1.0f / 4096.0f);
    float v = Q * (1.0f / 4096.0f) - m * m;
    float a = gamma[dg] * rsqrtf(v + 1e-5f);
    A[dg] = a;
    C[dg] = beta[dg] - m * a;
  }
}

__global__ __launch_bounds__(256) void head_kernel(
    const float* __restrict__ z, const float* __restrict__ A,
    const float* __restrict__ C, const float* __restrict__ w2,
    const float* __restrict__ b2, const float* __restrict__ t,
    float* __restrict__ out, float* __restrict__ bce) {
  const int tid = threadIdx.x;
  const int wv = tid >> 6, lane = tid & 63;
  const int b = blockIdx.x * 4 + wv;
  float4 A4 = ((const float4*)A)[lane];
  float4 C4 = ((const float4*)C)[lane];
  float4 w24 = ((const float4*)w2)[lane];
  float4 zv = ((const float4*)z)[(size_t)b * 64 + lane];
  float h0 = fmaxf(A4.x * zv.x + C4.x, 0.f);
  float h1 = fmaxf(A4.y * zv.y + C4.y, 0.f);
  float h2 = fmaxf(A4.z * zv.z + C4.z, 0.f);
  float h3 = fmaxf(A4.w * zv.w + C4.w, 0.f);
  float part = h0 * w24.x + h1 * w24.y + h2 * w24.z + h3 * w24.w;
#pragma unroll
  for (int off = 32; off > 0; off >>= 1) part += __shfl_down(part, off);
  if (lane == 0) {
    float logit = part + b2[0];
    out[1 + b] = logit;
    float tb = t[b];
    bce[b] = fmaxf(logit, 0.f) - logit * tb + log1pf(expf(-fabsf(logit)));
  }
}

__global__ __launch_bounds__(256) void loss_kernel(const float* __restrict__ bce,
                                                   float* __restrict__ out) {
  __shared__ float red[4];
  const int tid = threadIdx.x;
  float s = 0.f;
  for (int i = 0; i < 16; i++) s += bce[tid + i * 256];
#pragma unroll
  for (int off = 32; off > 0; off >>= 1) s += __shfl_down(s, off);
  if ((tid & 63) == 0) red[tid >> 6] = s;
  __syncthreads();
  if (tid == 0) out[0] = (red[0] + red[1] + red[2] + red[3]) * (1.0f / 4096.0f);
}

extern "C" void kernel_launch(void* const* d_in, const int* in_sizes, int n_in,
                              void* d_out, int out_size, void* d_ws, size_t ws_size,
                              hipStream_t stream) {
  const int* tokens = (const int*)d_in[0];
  const int* lengths = (const int*)d_in[1];
  const float* t = (const float*)d_in[2];
  const float* emb = (const float*)d_in[3];
  const float* W1 = (const float*)d_in[4];
  const float* b1 = (const float*)d_in[5];
  const float* gamma = (const float*)d_in[6];
  const float* beta = (const float*)d_in[7];
  const float* w2 = (const float*)d_in[8];
  const float* b2 = (const float*)d_in[9];
  float* out = (float*)d_out;

  float* wsf = (float*)d_ws;
  float* pooled = wsf;                 // 1,048,576 floats
  float* z = wsf + 1048576;            // 1,048,576
  float* W1p = wsf + 2097152;          // 65,536
  float* psum = wsf + 2162688;         // 65,536 (256 blocks x 256 dims)
  float* psq = wsf + 2228224;          // 65,536
  float* A = wsf + 2293760;            // 256
  float* C = wsf + 2294016;            // 256
  float* bce = wsf + 2294272;          // 4,096 (fallback path only)
  float* bpart = wsf + 2298368;        // 256
  // total ~8.77 MiB of d_ws

  void* args[] = {(void*)&tokens, (void*)&lengths, (void*)&t, (void*)&emb,
                  (void*)&W1, (void*)&b1, (void*)&gamma, (void*)&beta,
                  (void*)&w2, (void*)&b2, (void*)&pooled, (void*)&z,
                  (void*)&W1p, (void*)&psum, (void*)&psq, (void*)&A,
                  (void*)&C, (void*)&bpart, (void*)&out};
  hipError_t err = hipLaunchCooperativeKernel((void*)fused_kernel, dim3(256),
                                              dim3(256), args, 0, stream);
  if (err != hipSuccess) {
    (void)hipGetLastError();   // clear error state; fall back to 5-kernel path
    pool_pack_kernel<<<2048, 256, 0, stream>>>(tokens, lengths, emb, pooled, W1, W1p);
    gemm_stats_kernel<<<256, 256, 0, stream>>>(pooled, W1p, b1, z, psum, psq);
    bn_reduce_kernel<<<16, 256, 0, stream>>>(psum, psq, gamma, beta, A, C);
    head_kernel<<<1024, 256, 0, stream>>>(z, A, C, w2, b2, t, out, bce);
    loss_kernel<<<1, 256, 0, stream>>>(bce, out);
  }
}

// Round 2
// 242.688 us; speedup vs baseline: 1.6331x; 1.6331x over previous
//
#include <hip/hip_runtime.h>
#include <math.h>

#define L_ 200

// ---------------- K1: transpose-pack W1 [256][256] -> W1p[kb][d] ----------------
// W1p float4 at [kb*256 + d] holds W1[d][4kb..4kb+3] (K-minor pack for gemm).
__global__ __launch_bounds__(256) void pack_kernel(const float* __restrict__ W1,
                                                   float* __restrict__ W1p) {
  const int tid = threadIdx.x;
  float4 v = ((const float4*)W1)[tid * 64 + blockIdx.x];
  ((float4*)W1p)[blockIdx.x * 256 + tid] = v;
}

// ---------------- K2: pool 2 rows/block (verified structure) + fused GEMM tile --
// Pool: 2 waves per row (halves), 4-deep gather ILP, pooled kept in LDS only.
// GEMM: K split across 4 waves (disjoint 64KB W1p slices), LDS tree-reduce,
// z + b1 written to global; BN partials written TRANSPOSED for coalesced K3.
__global__ __launch_bounds__(256) void pool_gemm_kernel(
    const int* __restrict__ tokens, const int* __restrict__ lengths,
    const float* __restrict__ emb, const float* __restrict__ W1p,
    const float* __restrict__ b1, float* __restrict__ z,
    float* __restrict__ psumT, float* __restrict__ psqT) {
  __shared__ float4 PART[2][64];        // half-merge buffer
  __shared__ float4 SHP[2][64];         // pooled rows (stay in LDS)
  __shared__ float4 SRED4[4][2][64];    // cross-wave gemm partials (8 KB)
  const int tid = threadIdx.x;
  const int wv = tid >> 6, lane = tid & 63;
  const int pair = wv >> 1, half = wv & 1;
  const int row = blockIdx.x * 2 + pair;
  const int len = lengths[row];
  const int* trow = tokens + row * L_;
  const float4* embv = (const float4*)emb;

  // ---- pool phase (verified 4-deep gather) ----
  float4 a0 = make_float4(0.f, 0.f, 0.f, 0.f);
  float4 a1 = a0, a2 = a0, a3 = a0;
  for (int l0 = half * 64; l0 < len; l0 += 128) {
    int nt = len - l0; nt = nt > 64 ? 64 : nt;
    int tk = (lane < nt) ? trow[l0 + lane] : 0;   // coalesced token load
    int j = 0;
    for (; j + 4 <= nt; j += 4) {
      int t0 = __shfl(tk, j);
      int t1 = __shfl(tk, j + 1);
      int t2 = __shfl(tk, j + 2);
      int t3 = __shfl(tk, j + 3);
      float4 v0 = embv[(size_t)t0 * 64 + lane];
      float4 v1 = embv[(size_t)t1 * 64 + lane];
      float4 v2 = embv[(size_t)t2 * 64 + lane];
      float4 v3 = embv[(size_t)t3 * 64 + lane];
      a0.x += v0.x; a0.y += v0.y; a0.z += v0.z; a0.w += v0.w;
      a1.x += v1.x; a1.y += v1.y; a1.z += v1.z; a1.w += v1.w;
      a2.x += v2.x; a2.y += v2.y; a2.z += v2.z; a2.w += v2.w;
      a3.x += v3.x; a3.y += v3.y; a3.z += v3.z; a3.w += v3.w;
    }
    for (; j < nt; j++) {
      int t0 = __shfl(tk, j);
      float4 v0 = embv[(size_t)t0 * 64 + lane];
      a0.x += v0.x; a0.y += v0.y; a0.z += v0.z; a0.w += v0.w;
    }
  }
  float4 r;
  r.x = (a0.x + a1.x) + (a2.x + a3.x);
  r.y = (a0.y + a1.y) + (a2.y + a3.y);
  r.z = (a0.z + a1.z) + (a2.z + a3.z);
  r.w = (a0.w + a1.w) + (a2.w + a3.w);
  if (half) PART[pair][lane] = r;
  __syncthreads();
  if (!half) {
    float4 o = PART[pair][lane];
    const float inv = 1.0f / (float)len;
    r.x = (r.x + o.x) * inv;
    r.y = (r.y + o.y) * inv;
    r.z = (r.z + o.z) * inv;
    r.w = (r.w + o.w) * inv;
    SHP[pair][lane] = r;      // pooled row stays in LDS; no global roundtrip
  }
  __syncthreads();

  // ---- gemm phase: wave wv handles K-blocks [wv*16, wv*16+16) ----
  const float4* w4 = (const float4*)W1p;
  float acc0[4] = {0.f, 0.f, 0.f, 0.f};
  float acc1[4] = {0.f, 0.f, 0.f, 0.f};
  const int kb0 = wv * 16;
  for (int kk = 0; kk < 16; kk++) {
    const int kb = kb0 + kk;
    float4 p0 = SHP[0][kb];   // wave-uniform -> LDS broadcast
    float4 p1 = SHP[1][kb];
    float4 wk0 = w4[kb * 256 + lane * 4 + 0];
    float4 wk1 = w4[kb * 256 + lane * 4 + 1];
    float4 wk2 = w4[kb * 256 + lane * 4 + 2];
    float4 wk3 = w4[kb * 256 + lane * 4 + 3];
    acc0[0] += p0.x * wk0.x + p0.y * wk0.y + p0.z * wk0.z + p0.w * wk0.w;
    acc0[1] += p0.x * wk1.x + p0.y * wk1.y + p0.z * wk1.z + p0.w * wk1.w;
    acc0[2] += p0.x * wk2.x + p0.y * wk2.y + p0.z * wk2.z + p0.w * wk2.w;
    acc0[3] += p0.x * wk3.x + p0.y * wk3.y + p0.z * wk3.z + p0.w * wk3.w;
    acc1[0] += p1.x * wk0.x + p1.y * wk0.y + p1.z * wk0.z + p1.w * wk0.w;
    acc1[1] += p1.x * wk1.x + p1.y * wk1.y + p1.z * wk1.z + p1.w * wk1.w;
    acc1[2] += p1.x * wk2.x + p1.y * wk2.y + p1.z * wk2.z + p1.w * wk2.w;
    acc1[3] += p1.x * wk3.x + p1.y * wk3.y + p1.z * wk3.z + p1.w * wk3.w;
  }
  // output dim for (lane, j) is d = lane*4 + j; store float4 (conflict-free),
  // read back as scalars (consecutive banks).
  SRED4[wv][0][lane] = make_float4(acc0[0], acc0[1], acc0[2], acc0[3]);
  SRED4[wv][1][lane] = make_float4(acc1[0], acc1[1], acc1[2], acc1[3]);
  __syncthreads();
  const float* SREDf = (const float*)SRED4;   // layout [w][r][256]
  const float bb = b1[tid];
  float z0 = bb, z1 = bb;
#pragma unroll
  for (int w = 0; w < 4; w++) {
    z0 += SREDf[(w * 2 + 0) * 256 + tid];
    z1 += SREDf[(w * 2 + 1) * 256 + tid];
  }
  const int r0 = blockIdx.x * 2;
  z[(size_t)r0 * 256 + tid] = z0;              // coalesced
  z[(size_t)(r0 + 1) * 256 + tid] = z1;
  // transposed partials: psumT[d][block] -> coalesced reads in bn_reduce
  psumT[(size_t)tid * 2048 + blockIdx.x] = z0 + z1;
  psqT[(size_t)tid * 2048 + blockIdx.x] = z0 * z0 + z1 * z1;
}

// ---------------- K3: BN finalize; block d reduces 2048 partials ----------------
__global__ __launch_bounds__(256) void bn_reduce_kernel(
    const float* __restrict__ psumT, const float* __restrict__ psqT,
    const float* __restrict__ gamma, const float* __restrict__ beta,
    float* __restrict__ A, float* __restrict__ C) {
  const int tid = threadIdx.x;
  const int wv = tid >> 6, lane = tid & 63;
  const int d = blockIdx.x;
  const float* ps = psumT + (size_t)d * 2048;
  const float* pq = psqT + (size_t)d * 2048;
  float s = 0.f, q = 0.f;
#pragma unroll
  for (int i = 0; i < 8; i++) {      // coalesced 1KB chunks
    s += ps[i * 256 + tid];
    q += pq[i * 256 + tid];
  }
#pragma unroll
  for (int off = 32; off > 0; off >>= 1) {
    s += __shfl_down(s, off);
    q += __shfl_down(q, off);
  }
  __shared__ float sl[4], ql[4];
  if (lane == 0) { sl[wv] = s; ql[wv] = q; }
  __syncthreads();
  if (tid == 0) {
    float S = (sl[0] + sl[1]) + (sl[2] + sl[3]);
    float Q = (ql[0] + ql[1]) + (ql[2] + ql[3]);
    float m = S * (1.0f / 4096.0f);
    float v = Q * (1.0f / 4096.0f) - m * m;
    float a = gamma[d] * rsqrtf(v + 1e-5f);
    A[d] = a;
    C[d] = beta[d] - m * a;
  }
}

// ---------------- K4: BN-apply + ReLU + dot head + per-row BCE (verified) -------
__global__ __launch_bounds__(256) void head_kernel(
    const float* __restrict__ z, const float* __restrict__ A,
    const float* __restrict__ C, const float* __restrict__ w2,
    const float* __restrict__ b2, const float* __restrict__ t,
    float* __restrict__ out, float* __restrict__ bce) {
  const int tid = threadIdx.x;
  const int wv = tid >> 6, lane = tid & 63;
  const int b = blockIdx.x * 4 + wv;
  float4 A4 = ((const float4*)A)[lane];
  float4 C4 = ((const float4*)C)[lane];
  float4 w24 = ((const float4*)w2)[lane];
  float4 zv = ((const float4*)z)[(size_t)b * 64 + lane];
  float h0 = fmaxf(A4.x * zv.x + C4.x, 0.f);
  float h1 = fmaxf(A4.y * zv.y + C4.y, 0.f);
  float h2 = fmaxf(A4.z * zv.z + C4.z, 0.f);
  float h3 = fmaxf(A4.w * zv.w + C4.w, 0.f);
  float part = h0 * w24.x + h1 * w24.y + h2 * w24.z + h3 * w24.w;
#pragma unroll
  for (int off = 32; off > 0; off >>= 1) part += __shfl_down(part, off);
  if (lane == 0) {
    float logit = part + b2[0];
    out[1 + b] = logit;
    float tb = t[b];
    bce[b] = fmaxf(logit, 0.f) - logit * tb + log1pf(expf(-fabsf(logit)));
  }
}

// ---------------- K5: deterministic loss reduction (verified) -------------------
__global__ __launch_bounds__(256) void loss_kernel(const float* __restrict__ bce,
                                                   float* __restrict__ out) {
  __shared__ float red[4];
  const int tid = threadIdx.x;
  float s = 0.f;
  for (int i = 0; i < 16; i++) s += bce[tid + i * 256];
#pragma unroll
  for (int off = 32; off > 0; off >>= 1) s += __shfl_down(s, off);
  if ((tid & 63) == 0) red[tid >> 6] = s;
  __syncthreads();
  if (tid == 0) out[0] = (red[0] + red[1] + red[2] + red[3]) * (1.0f / 4096.0f);
}

extern "C" void kernel_launch(void* const* d_in, const int* in_sizes, int n_in,
                              void* d_out, int out_size, void* d_ws, size_t ws_size,
                              hipStream_t stream) {
  const int* tokens = (const int*)d_in[0];
  const int* lengths = (const int*)d_in[1];
  const float* t = (const float*)d_in[2];
  const float* emb = (const float*)d_in[3];
  const float* W1 = (const float*)d_in[4];
  const float* b1 = (const float*)d_in[5];
  const float* gamma = (const float*)d_in[6];
  const float* beta = (const float*)d_in[7];
  const float* w2 = (const float*)d_in[8];
  const float* b2 = (const float*)d_in[9];
  float* out = (float*)d_out;

  float* wsf = (float*)d_ws;
  float* z = wsf;                      // 1,048,576 floats
  float* W1p = wsf + 1048576;          // 65,536
  float* psumT = wsf + 1114112;        // 524,288 (256 dims x 2048 blocks)
  float* psqT = wsf + 1638400;         // 524,288
  float* A = wsf + 2162688;            // 256
  float* C = wsf + 2162944;            // 256
  float* bce = wsf + 2163200;          // 4,096
  // total ~8.67 MiB of d_ws

  pack_kernel<<<64, 256, 0, stream>>>(W1, W1p);
  pool_gemm_kernel<<<2048, 256, 0, stream>>>(tokens, lengths, emb, W1p, b1,
                                             z, psumT, psqT);
  bn_reduce_kernel<<<256, 256, 0, stream>>>(psumT, psqT, gamma, beta, A, C);
  head_kernel<<<1024, 256, 0, stream>>>(z, A, C, w2, b2, t, out, bce);
  loss_kernel<<<1, 256, 0, stream>>>(bce, out);
}